// Round 7
// baseline (334.100 us; speedup 1.0000x reference)
//
#include <hip/hip_runtime.h>

typedef float v4f __attribute__((ext_vector_type(4)));

#define BDIM   256
#define KK     9
#define CELLS  81
#define BOARD  729
#define BPB    4                 // boards per block
#define CHUNK  (BPB * BOARD)     // 2916 floats = exactly 729 v4f (16B-aligned per block)
#define NV4    (CHUNK / 4)       // 729

// async global->LDS, 16B per lane, wave-uniform base + lane*16 layout (our
// block-linear staging matches the HW scatter pattern exactly).
__device__ __forceinline__ void ld_g2l_16(const float* g, float* l) {
    __builtin_amdgcn_global_load_lds(
        (const __attribute__((address_space(1))) unsigned int*)g,
        (__attribute__((address_space(3))) unsigned int*)l,
        16, 0, 0);
}

__global__ __launch_bounds__(BDIM) void sudoku_iter_kernel(
    const float* __restrict__ sudoku,
    const float* __restrict__ rmask,
    const float* __restrict__ rindex,
    const float* __restrict__ conv_w,
    const float* __restrict__ conv_b,
    float* __restrict__ out,
    int Btot)
{
    __shared__ __align__(16) float sA[CHUNK];   // sudoku (11664 B)
    __shared__ __align__(16) float sR[CHUNK];   // rmask  (11664 B)
    __shared__ int   meta_e[BPB];
    __shared__ int   meta_cell[BPB];
    __shared__ float meta_m[BPB];
    __shared__ float meta_cms[BPB];
    __shared__ float meta_ri[BPB];

    const int tid = threadIdx.x;
    const int blk = blockIdx.x;
    const size_t base = (size_t)blk * CHUNK;

    // ---- phase 1: pure async DMA staging, zero VGPR, cannot be sunk ----
    const float* gA = sudoku + base;
    const float* gR = rmask  + base;
    #pragma unroll
    for (int j = 0; j < 3; ++j) {
        int idx = j * BDIM + tid;            // v4f index 0..767
        if (idx < NV4) ld_g2l_16(gA + idx * 4, &sA[idx * 4]);
    }
    #pragma unroll
    for (int j = 0; j < 3; ++j) {
        int idx = j * BDIM + tid;
        if (idx < NV4) ld_g2l_16(gR + idx * 4, &sR[idx * 4]);
    }

    // uniform params (scalarized s_loads, issue early)
    float wreg[KK];
    #pragma unroll
    for (int n = 0; n < KK; ++n) wreg[n] = conv_w[n];
    const float bias = conv_b[0];
    const float cmp  = fminf(fmaxf(bias, 0.f), 1.f);

    __syncthreads();   // drains the DMA (vmcnt(0)) — the only real barrier

    // ---- phase 2: per-wave selection on its own board (from LDS) ----
    {
        const int wave = tid >> 6;
        const int lane = tid & 63;
        const float* bs = sA + wave * BOARD;

        float v0; int i0;
        {
            const int cell = lane;
            float cnt = bias;
            #pragma unroll
            for (int n = 0; n < KK; ++n) cnt += bs[n * CELLS + cell] * wreg[n];
            float nic = fmaxf(cnt - 1.f, 0.f);
            float m0  = fminf(fmaxf(1.f - nic, 0.f), 1.f) * (-(float)KK);
            v0 = m0 - nic; i0 = cell;
        }
        if (lane < CELLS - 64) {       // cells 64..80
            const int cell = lane + 64;
            float cnt = bias;
            #pragma unroll
            for (int n = 0; n < KK; ++n) cnt += bs[n * CELLS + cell] * wreg[n];
            float nic = fmaxf(cnt - 1.f, 0.f);
            float m0  = fminf(fmaxf(1.f - nic, 0.f), 1.f) * (-(float)KK);
            float v1 = m0 - nic;
            if (v1 > v0) { v0 = v1; i0 = cell; }   // strict > keeps first max
        }
        #pragma unroll
        for (int off = 32; off > 0; off >>= 1) {
            float ov = __shfl_xor(v0, off, 64);
            int   oi = __shfl_xor(i0, off, 64);
            if (ov > v0 || (ov == v0 && oi < i0)) { v0 = ov; i0 = oi; }
        }
        // all lanes hold the winning cell; same-address LDS reads broadcast free
        const int cellstar = i0;
        float m = bs[cellstar]; int nstar = 0;
        #pragma unroll
        for (int n = 1; n < KK; ++n) {
            float v = bs[n * CELLS + cellstar];
            if (v > m) { m = v; nstar = n; }
        }
        if (lane == 0) {
            meta_e[wave]    = nstar * CELLS + cellstar;
            meta_cell[wave] = cellstar;
            meta_m[wave]    = m;
            meta_cms[wave]  = fminf(fmaxf(m * wreg[nstar] + bias, 0.f), 1.f);
            meta_ri[wave]   = rindex[blk * BPB + wave];
        }
    }
    __syncthreads();   // lgkm-only drain (no vm ops pending) — near free

    // ---- phase 3: block-linear epilogue, LDS reads + fire-and-forget stores ----
    v4f* os4 = (v4f*)(out + base);
    v4f* or4 = (v4f*)(out + (size_t)Btot * BOARD + base);
    const v4f* sA4 = (const v4f*)sA;
    const v4f* sR4 = (const v4f*)sR;

    const int c0 = (4 * tid) % 81;
    const int iadd[3] = {0, 52, 23};        // (1024*i) % 81

    #pragma unroll
    for (int i = 0; i < 3; ++i) {
        int g = tid + i * BDIM;
        if (g < NV4) {
            v4f s4 = sA4[g];
            v4f r4 = sR4[g];
            float so[4], ro[4];
            const float* sp = (const float*)&s4;
            const float* rp = (const float*)&r4;
            #pragma unroll
            for (int j = 0; j < 4; ++j) {
                int f = 4 * g + j;
                int blj = (f >= 1458) ? (f >= 2187 ? 3 : 2) : (f >= 729 ? 1 : 0);
                int e = f - blj * BOARD;
                int cell = c0 + iadd[i] + j;
                if (cell >= CELLS) cell -= CELLS;
                float s  = sp[j];
                float rm = rp[j];
                float mm  = meta_m[blj];
                float riv = meta_ri[blj];
                float ov  = (e == meta_e[blj]) ? mm : 0.f;
                float cm  = (cell == meta_cell[blj]) ? meta_cms[blj] : cmp;
                float orm = s * cm * (1.f - ov);
                float rmo = fmaxf(rm, riv * orm);
                rmo = fmaxf(rmo, (riv - 1.f) * ov);
                so[j] = s * (1.f - orm);
                ro[j] = rmo;
            }
            v4f sv; sv.x = so[0]; sv.y = so[1]; sv.z = so[2]; sv.w = so[3];
            v4f rv; rv.x = ro[0]; rv.y = ro[1]; rv.z = ro[2]; rv.w = ro[3];
            __builtin_nontemporal_store(sv, &os4[g]);
            __builtin_nontemporal_store(rv, &or4[g]);
        }
    }

    if (tid < BPB) {
        out[(size_t)Btot * BOARD * 2 + (size_t)blk * BPB + tid] = meta_ri[tid] + 1.f;
    }
}

extern "C" void kernel_launch(void* const* d_in, const int* in_sizes, int n_in,
                              void* d_out, int out_size, void* d_ws, size_t ws_size,
                              hipStream_t stream) {
    const float* sudoku = (const float*)d_in[0];
    const float* rmask  = (const float*)d_in[1];
    const float* rindex = (const float*)d_in[2];
    const float* conv_w = (const float*)d_in[3];
    const float* conv_b = (const float*)d_in[4];
    float* out = (float*)d_out;

    const int Btot = in_sizes[2];            // 32768 boards
    const int nblocks = Btot / BPB;          // 8192

    sudoku_iter_kernel<<<nblocks, BDIM, 0, stream>>>(
        sudoku, rmask, rindex, conv_w, conv_b, out, Btot);
}

// Round 8
// 330.143 us; speedup vs baseline: 1.0120x; 1.0120x over previous
//
#include <hip/hip_runtime.h>

typedef float v4f __attribute__((ext_vector_type(4)));

#define BDIM   256
#define KK     9
#define CELLS  81
#define BOARD  729
#define BPB    4      // one board per wave, 4 waves per block

// Zero-LDS, zero-barrier design: each wave owns one board end to end.
// Select phase reads the board with 9 (+9 masked) coalesced strided loads;
// apply phase re-reads it as v4f (L1/L2-hot) plus rmask, and nt-stores.
__global__ __launch_bounds__(BDIM) void sudoku_iter_kernel(
    const float* __restrict__ sudoku,
    const float* __restrict__ rmask,
    const float* __restrict__ rindex,
    const float* __restrict__ conv_w,
    const float* __restrict__ conv_b,
    float* __restrict__ out,
    int Btot)
{
    const int tid   = threadIdx.x;
    const int lane  = tid & 63;
    const int board = blockIdx.x * BPB + (tid >> 6);
    const unsigned fs = (unsigned)board * BOARD;       // global float index of board start
    const float* bs = sudoku + fs;

    // ---- select: direct coalesced loads, no LDS ----
    float a[KK];
    #pragma unroll
    for (int n = 0; n < KK; ++n) a[n] = bs[n * CELLS + lane];          // cells 0..63
    const bool hi = (lane < CELLS - 64);
    float b[KK];
    #pragma unroll
    for (int n = 0; n < KK; ++n) b[n] = hi ? bs[n * CELLS + 64 + lane] : 0.f;  // cells 64..80

    float wreg[KK];
    #pragma unroll
    for (int n = 0; n < KK; ++n) wreg[n] = conv_w[n];
    const float bias = conv_b[0];
    const float cmp  = fminf(fmaxf(bias, 0.f), 1.f);
    const float ri   = rindex[board];                  // wave-uniform

    float v0; int i0;
    {
        float cnt = bias;
        #pragma unroll
        for (int n = 0; n < KK; ++n) cnt += a[n] * wreg[n];
        float nic = fmaxf(cnt - 1.f, 0.f);
        float m0  = fminf(fmaxf(1.f - nic, 0.f), 1.f) * (-(float)KK);
        v0 = m0 - nic; i0 = lane;
    }
    if (hi) {
        float cnt = bias;
        #pragma unroll
        for (int n = 0; n < KK; ++n) cnt += b[n] * wreg[n];
        float nic = fmaxf(cnt - 1.f, 0.f);
        float m0  = fminf(fmaxf(1.f - nic, 0.f), 1.f) * (-(float)KK);
        float v1 = m0 - nic;
        if (v1 > v0) { v0 = v1; i0 = lane + 64; }      // strict > keeps first max
    }
    #pragma unroll
    for (int off = 32; off > 0; off >>= 1) {
        float ov = __shfl_xor(v0, off, 64);
        int   oi = __shfl_xor(i0, off, 64);
        if (ov > v0 || (ov == v0 && oi < i0)) { v0 = ov; i0 = oi; }
    }
    const int cellstar = __builtin_amdgcn_readfirstlane(i0);   // uniform -> scalarize

    // number argmax at the chosen cell: 9 scalar (SMEM-able) broadcast loads, L1-hot
    float m = bs[cellstar]; int nstar = 0;
    #pragma unroll
    for (int n = 1; n < KK; ++n) {
        float v = bs[n * CELLS + cellstar];
        if (v > m) { m = v; nstar = n; }
    }
    const int   es  = nstar * CELLS + cellstar;
    const float cms = fminf(fmaxf(m * wreg[nstar] + bias, 0.f), 1.f);

    // ---- apply: board geometry (start only 4B-aligned; 729 odd) ----
    const unsigned G_lo = (fs + 3) >> 2;               // first aligned global v4f
    const unsigned G_hi = (fs + BOARD) >> 2;           // one past last
    const int h  = (int)(4 * G_lo - fs);               // head floats 0..3
    const int t  = (int)(fs + BOARD - 4 * G_hi);       // tail floats 0..3
    const int n4 = (int)(G_hi - G_lo);                 // 181 or 182

    const v4f* gs4 = (const v4f*)sudoku;
    const v4f* gr4 = (const v4f*)rmask;
    v4f* os4 = (v4f*)out;
    v4f* or4 = (v4f*)(out + (size_t)Btot * BOARD);

    v4f s4[3], r4[3];
    bool act[3];
    #pragma unroll
    for (int i = 0; i < 3; ++i) {
        int k = lane + 64 * i;
        act[i] = (k < n4);
        if (act[i]) s4[i] = gs4[G_lo + k];             // L1/L2-hot (just read above)
    }
    #pragma unroll
    for (int i = 0; i < 3; ++i) {
        if (act[i]) r4[i] = gr4[G_lo + lane + 64 * i];
    }
    const bool hasH = (lane < h);
    const bool hasT = (lane >= 8) && (lane < 8 + t);
    const int  eH   = lane;
    const int  eT   = BOARD - t + (lane - 8);
    float shd = 0.f, std_ = 0.f, rhd = 0.f, rtd = 0.f;
    if (hasH) { shd = sudoku[fs + eH]; rhd = rmask[fs + eH]; }
    if (hasT) { std_ = sudoku[fs + eT]; rtd = rmask[fs + eT]; }

    const int cbase = (h + 4 * lane) % CELLS;
    const int iadd[3] = {0, 13, 26};                   // (256*i) % 81

    #pragma unroll
    for (int i = 0; i < 3; ++i) {
        if (act[i]) {
            float so[4], ro[4];
            const float* sp = (const float*)&s4[i];
            const float* rp = (const float*)&r4[i];
            #pragma unroll
            for (int j = 0; j < 4; ++j) {
                int e = h + 4 * (lane + 64 * i) + j;   // element within board
                int cell = cbase + iadd[i] + j;
                if (cell >= CELLS) cell -= CELLS;
                float s  = sp[j];
                float rm = rp[j];
                float ov  = (e == es) ? m : 0.f;
                float cm  = (cell == cellstar) ? cms : cmp;
                float orm = s * cm * (1.f - ov);
                float rmo = fmaxf(rm, ri * orm);
                rmo = fmaxf(rmo, (ri - 1.f) * ov);
                so[j] = s * (1.f - orm);
                ro[j] = rmo;
            }
            v4f sv; sv.x = so[0]; sv.y = so[1]; sv.z = so[2]; sv.w = so[3];
            v4f rv; rv.x = ro[0]; rv.y = ro[1]; rv.z = ro[2]; rv.w = ro[3];
            unsigned g = G_lo + lane + 64 * i;
            __builtin_nontemporal_store(sv, &os4[g]);
            __builtin_nontemporal_store(rv, &or4[g]);
        }
    }
    if (hasH | hasT) {
        int   e  = hasH ? eH : eT;
        float s  = hasH ? shd : std_;
        float rm = hasH ? rhd : rtd;
        int cell = (e >= 648) ? (e - 648) : e;         // head e<=2; tail e>=726
        float ov  = (e == es) ? m : 0.f;
        float cm  = (cell == cellstar) ? cms : cmp;
        float orm = s * cm * (1.f - ov);
        float rmo = fmaxf(rm, ri * orm);
        rmo = fmaxf(rmo, (ri - 1.f) * ov);
        __builtin_nontemporal_store(s * (1.f - orm), out + fs + e);
        __builtin_nontemporal_store(rmo, out + (size_t)Btot * BOARD + fs + e);
    }

    if (lane == 0) {
        out[(size_t)Btot * BOARD * 2 + board] = ri + 1.f;
    }
}

extern "C" void kernel_launch(void* const* d_in, const int* in_sizes, int n_in,
                              void* d_out, int out_size, void* d_ws, size_t ws_size,
                              hipStream_t stream) {
    const float* sudoku = (const float*)d_in[0];
    const float* rmask  = (const float*)d_in[1];
    const float* rindex = (const float*)d_in[2];
    const float* conv_w = (const float*)d_in[3];
    const float* conv_b = (const float*)d_in[4];
    float* out = (float*)d_out;

    const int Btot = in_sizes[2];            // 32768 boards
    const int nblocks = Btot / BPB;          // 8192 blocks, 1 board per wave

    sudoku_iter_kernel<<<nblocks, BDIM, 0, stream>>>(
        sudoku, rmask, rindex, conv_w, conv_b, out, Btot);
}